// Round 4
// baseline (176.340 us; speedup 1.0000x reference)
//
#include <hip/hip_runtime.h>

#define NPIX 16384
#define IMW  128

__device__ __forceinline__ int find_root(int* L, int a){
    int p = L[a];
    while(p != a){
        int gp = L[p];
        if(gp != p) L[a] = gp;   // path halving; benign race
        a = p; p = gp;
    }
    return a;
}

// Link-by-index (root hi -> lo): links strictly decrease => acyclic under
// concurrency. Roots are exactly nodes with L[n]==n after all unions.
__device__ __forceinline__ void unite(int* L, int a, int b){
    while(true){
        a = find_root(L, a);
        b = find_root(L, b);
        if(a == b) return;
        int hi = (a > b) ? a : b;
        int lo = (a > b) ? b : a;
        int old = atomicCAS(&L[hi], hi, lo);
        if(old == hi) return;
        a = old; b = lo;
    }
}

// One block per (ch, threshold, region): bitmask-run CCL (as R3). Each block
// publishes its betti pair (agent-scope), bumps a device counter; the LAST
// block to finish runs the whole rows+final phase in-place (2 rows at a time),
// eliminating two kernel launches + a d_out memset.
__global__ __launch_bounds__(256) void fused_kernel(const float* __restrict__ prob,
                                                    const int*   __restrict__ sel,
                                                    const float* __restrict__ gt,
                                                    unsigned*    __restrict__ cnt,
                                                    float*       __restrict__ betti,
                                                    float*       __restrict__ out){
    __shared__ unsigned long long M[256];   // row masks: word w = (row<<1)|half
    __shared__ unsigned long long S[256];   // run-start masks
    __shared__ int L[8192];                 // union-find arena (32 KB), reused by rows phase
    __shared__ int red[12];
    __shared__ float fred[8];
    __shared__ int lastFlag;

    const int tid = threadIdx.x, bid = blockIdx.x;
    const int ch = bid / 400, t = (bid % 400) >> 2, r = bid & 3;
    const float th = (float)t / 99.0f;
    const float* img = prob + (size_t)(sel[r] * 3 + ch) * NPIX;

    {   // init union-find arena (vectorized)
        int4* L4 = (int4*)L;
        for(int i = tid; i < 2048; i += 256){ int b = i * 4; L4[i] = make_int4(b, b+1, b+2, b+3); }
    }

    // build bitmasks: wave's ballot over 64 consecutive pixels = one u64 word
    const int lane = tid & 63, wave = tid >> 6;
    for(int c = 0; c < 64; c++){
        float v = img[c * 256 + wave * 64 + lane];
        unsigned long long mm = __ballot(v > th);
        if(lane == 0) M[c * 4 + wave] = mm;
    }
    __syncthreads();

    // per-word masks & counts (thread <-> word)
    const int w = tid, row = w >> 1, half = w & 1;
    const unsigned long long m = M[w];
    const unsigned long long lcar = half ? (M[w - 1] >> 63) : 0ULL;
    const unsigned long long s = m & ~((m << 1) | lcar);
    S[w] = s;
    int pix   = __popcll(m);
    int edges = __popcll(m & ((m << 1) | lcar));           // horizontal pairs
    const unsigned long long va = (row > 0) ? M[w - 2] : 0ULL;
    edges += __popcll(m & va);                              // vertical pairs
    __syncthreads();

    const int base = half ? __popcll(S[w - 1]) : 0;         // runs in earlier word of row
    if(row > 0){
        unsigned long long c = m & va;
        const unsigned long long ccar = half ? ((M[w - 1] & M[w - 3]) >> 63) : 0ULL;
        unsigned long long cs = c & ~((c << 1) | ccar);     // contact-segment starts
        const unsigned long long sa = S[w - 2];
        const int basea = half ? __popcll(S[w - 3]) : 0;
        while(cs){
            const int x = __ffsll(cs) - 1;
            cs &= cs - 1;
            const unsigned long long lm = (2ULL << x) - 1;  // bits [0..x]
            const int na = (row - 1) * 64 + basea + __popcll(sa & lm) - 1;
            const int nb =  row      * 64 + base  + __popcll(s  & lm) - 1;
            unite(L, na, nb);
        }
    }
    __syncthreads();

    int b0 = 0;
    {   const int nrun = __popcll(s);
        for(int j = 0; j < nrun; j++){ const int n = row * 64 + base + j; b0 += (L[n] == n); } }

    for(int off = 32; off; off >>= 1){
        pix   += __shfl_down(pix,   off, 64);
        edges += __shfl_down(edges, off, 64);
        b0    += __shfl_down(b0,    off, 64);
    }
    if(lane == 0){ red[wave*3] = pix; red[wave*3+1] = edges; red[wave*3+2] = b0; }
    __syncthreads();
    if(tid == 0){
        int P = 0, E = 0, B = 0;
        for(int k = 0; k < 4; k++){ P += red[k*3]; E += red[k*3+1]; B += red[k*3+2]; }
        const float b0f = (float)B;
        const float b1f = b0f - ((float)P - (float)E);      // b1 = b0 - (pix - edges)
        const size_t o = (((size_t)ch * 100 + t) * 4 + r) * 2;
        __hip_atomic_store(&betti[o],     b0f, __ATOMIC_RELAXED, __HIP_MEMORY_SCOPE_AGENT);
        __hip_atomic_store(&betti[o + 1], b1f, __ATOMIC_RELAXED, __HIP_MEMORY_SCOPE_AGENT);
        const unsigned old = __hip_atomic_fetch_add(cnt, 1u, __ATOMIC_ACQ_REL, __HIP_MEMORY_SCOPE_AGENT);
        lastFlag = (old == 799u);
    }
    __syncthreads();
    if(!lastFlag) return;

    // ---------- rows + final phase (last block only) ----------
    // 24 rows, 2 at a time (128 threads each). LDS arrays carved from L.
    float* RB = (float*)L;
    const int sub = tid >> 7, lt = tid & 127;
    float* codes = RB + sub * 800;          // [100]
    float* birth = codes + 100;             // [99]
    float* bs0   = codes + 199;             // [99]
    float* bs1   = codes + 298;             // [99]
    float* gs0   = codes + 397;             // [99]
    float* gs1   = codes + 496;             // [99]
    float* gsh   = codes + 595;             // [198]
    const int chmap[6] = {0, 0, 1, 1, 0, 0};   // inside, boundary, union(=inside)

    float msum = 0.f, usum = 0.f;
    for(int chunk = 0; chunk < 12; chunk++){
        const int rowi = chunk * 2 + sub;   // 0..23
        const int rr = rowi / 6, j = rowi % 6;
        const int cch = chmap[j], comp = j & 1;
        if(lt < 100)
            codes[lt] = __hip_atomic_load(&betti[(((size_t)cch * 100 + lt) * 4 + rr) * 2 + comp],
                                          __ATOMIC_RELAXED, __HIP_MEMORY_SCOPE_AGENT);
        const float* g = gt + (size_t)rowi * 198;
        for(int i = lt; i < 198; i += 128) gsh[i] = g[i];
        __syncthreads();

        float b = 0.f, d = 0.f;
        if(lt < 99){
            const float dv = codes[lt + 1] - codes[lt];
            const float thv = (float)lt / 99.0f;
            b = (dv > 0.f) ? thv : 0.f;
            d = (dv < 0.f) ? thv : 0.f;
            birth[lt] = b;
        }
        __syncthreads();

        if(lt < 99){
            // stable sort by birth == stable partition (positive births ascending)
            int zb = 0, tz = 0;
            for(int k = 0; k < 99; k++){
                const int z = (birth[k] == 0.f) ? 1 : 0;
                tz += z;
                if(k < lt) zb += z;
            }
            const int pos = (b == 0.f) ? zb : (tz + lt - zb);
            bs0[pos] = b; bs1[pos] = d;

            const float gb = gsh[lt * 2];
            int rank = 0;
            for(int k = 0; k < 99; k++){
                const float o2 = gsh[k * 2];
                rank += (o2 < gb || (o2 == gb && k < lt)) ? 1 : 0;
            }
            gs0[rank] = gb; gs1[rank] = gsh[lt * 2 + 1];
        }
        __syncthreads();

        if(lt < 99){
            msum += fabsf(bs0[lt] - gs0[lt]) + fabsf(bs1[lt] - gs1[lt]);
            usum += d - b;
        }
        __syncthreads();   // arrays reused next chunk
    }

    for(int off = 32; off; off >>= 1){
        msum += __shfl_down(msum, off, 64);
        usum += __shfl_down(usum, off, 64);
    }
    if((tid & 63) == 0){ fred[(tid >> 6) * 2] = msum; fred[(tid >> 6) * 2 + 1] = usum; }
    __syncthreads();
    if(tid == 0){
        const float mm = fred[0] + fred[2] + fred[4] + fred[6];
        const float uu = fred[1] + fred[3] + fred[5] + fred[7];
        out[0] = mm / 2376.0f + uu / 24.0f;   // mean[4,6,99] + mean[4,6]
    }
}

extern "C" void kernel_launch(void* const* d_in, const int* in_sizes, int n_in,
                              void* d_out, int out_size, void* d_ws, size_t ws_size,
                              hipStream_t stream){
    const float* prob = (const float*)d_in[0];   // [4,3,128,128] f32
    const int*   sel  = (const int*)d_in[1];     // [4]
    const float* gt   = (const float*)d_in[2];   // [4,6,99,2] f32
    unsigned* cnt   = (unsigned*)d_ws;
    float*    betti = (float*)d_ws + 8;          // [2][100][4][2] = 1600 floats

    hipMemsetAsync(d_ws, 0, sizeof(unsigned), stream);
    fused_kernel<<<800, 256, 0, stream>>>(prob, sel, gt, cnt, betti, (float*)d_out);
}

// Round 5
// 119.783 us; speedup vs baseline: 1.4722x; 1.4722x over previous
//
#include <hip/hip_runtime.h>

#define NPIX 16384
typedef unsigned long long u64;

__device__ __forceinline__ int find_root(int* L, int a){
    int p = L[a];
    while(p != a){
        int gp = L[p];
        if(gp != p) L[a] = gp;   // path halving; benign race
        a = p; p = gp;
    }
    return a;
}

// Link-by-index (root hi -> lo): links strictly decrease => acyclic under
// concurrency. Roots are exactly nodes with L[n]==n after all unions.
__device__ __forceinline__ void unite(int* L, int a, int b){
    while(true){
        a = find_root(L, a);
        b = find_root(L, b);
        if(a == b) return;
        int hi = (a > b) ? a : b;
        int lo = (a > b) ? b : a;
        int old = atomicCAS(&L[hi], hi, lo);
        if(old == hi) return;
        a = old; b = lo;
    }
}

// One block per (ch, threshold, region). Rows as 2x u64 ballot-built bitmasks.
// pix/edges via popcounts. Union-find over RUNS. Unions are flattened into a
// block-wide worklist (prefix sum + binary search) so every wave-slot of the
// LDS pipe carries 64 active lanes instead of a divergent per-word tail.
// b0 = (#self-roots in arena) - (8192 - total_runs)  [conflict-free int2 scan].
__global__ __launch_bounds__(256) void ccl_kernel(const float* __restrict__ prob,
                                                  const int*   __restrict__ sel,
                                                  float*       __restrict__ betti,
                                                  float*       __restrict__ out){
    __shared__ u64 M[256];     // row masks: word w = (row<<1)|half
    __shared__ u64 S[256];     // run-start masks
    __shared__ u64 CS[256];    // contact-segment-start masks
    __shared__ int L[8192];    // union-find arena (32 KB)
    __shared__ int P[257];     // exclusive prefix of per-word contact counts
    __shared__ int red[16];
    const int tid = threadIdx.x, bid = blockIdx.x;
    if(bid == 0 && tid == 0) atomicExch(out, 0.0f);   // device-scope zero for rows' atomicAdd
    const int ch = bid / 400, t = (bid % 400) >> 2, r = bid & 3;
    const float th = (float)t / 99.0f;
    const float* img = prob + (size_t)(sel[r] * 3 + ch) * NPIX;

    {   // arena init, 8B stride => 2-way bank aliasing (free)
        int2* L2 = (int2*)L;
        for(int i = tid; i < 4096; i += 256) L2[i] = make_int2(2*i, 2*i + 1);
    }

    // build bitmasks: wave's ballot over 64 consecutive pixels = one u64 word
    const int lane = tid & 63, wave = tid >> 6;
    for(int c = 0; c < 64; c++){
        float v = img[c * 256 + wave * 64 + lane];
        u64 mm = __ballot(v > th);
        if(lane == 0) M[c * 4 + wave] = mm;
    }
    __syncthreads();

    // per-word masks & counts (thread <-> word)
    const int w = tid, row = w >> 1, half = w & 1;
    const u64 m = M[w];
    const u64 lcar = half ? (M[w - 1] >> 63) : 0ULL;
    const u64 s = m & ~((m << 1) | lcar);
    S[w] = s;
    int pix   = __popcll(m);
    int edges = __popcll(m & ((m << 1) | lcar));            // horizontal pairs
    const u64 va = (row > 0) ? M[w - 2] : 0ULL;
    edges += __popcll(m & va);                               // vertical pairs
    u64 csm = 0ULL;
    if(row > 0){
        const u64 c = m & va;
        const u64 ccar = half ? ((M[w - 1] & M[w - 3]) >> 63) : 0ULL;
        csm = c & ~((c << 1) | ccar);                        // contact-segment starts
    }
    CS[w] = csm;
    const int cw   = __popcll(csm);
    const int runs = __popcll(s);

    // exclusive prefix sum of cw over the 256 words
    int incl = cw;
    for(int off = 1; off < 64; off <<= 1){
        int n = __shfl_up(incl, off, 64);
        if(lane >= off) incl += n;
    }
    if(lane == 63) red[wave] = incl;
    __syncthreads();
    int woff = 0;
    for(int k = 0; k < wave; k++) woff += red[k];
    const int excl = woff + incl - cw;
    P[w] = excl;
    if(w == 255) P[256] = excl + cw;
    __syncthreads();
    const int C = P[256];

    // flat coherent union loop: lane j handles the j-th contact segment
    for(int j = tid; j < C; j += 256){
        int lo = 0, hi = 256;
        #pragma unroll
        for(int itv = 0; itv < 8; itv++){ int mid = (lo + hi) >> 1; if(P[mid] <= j) lo = mid; else hi = mid; }
        const int ww = lo, k = j - P[ww];
        u64 cs = CS[ww];
        for(int q = 0; q < k; q++) cs &= cs - 1;             // select k-th set bit
        const int x = __ffsll(cs) - 1;
        const u64 lm = (2ULL << x) - 1;                      // bits [0..x]
        const int rw = ww >> 1, hf = ww & 1;
        const int base  = hf ? __popcll(S[ww - 1]) : 0;
        const int basea = hf ? __popcll(S[ww - 3]) : 0;
        const int nb =  rw      * 64 + base  + __popcll(S[ww]     & lm) - 1;
        const int na = (rw - 1) * 64 + basea + __popcll(S[ww - 2] & lm) - 1;
        unite(L, na, nb);
    }
    __syncthreads();

    // conflict-free root count over the whole arena
    int rc = 0;
    const int2* L2c = (const int2*)L;
    for(int i = tid; i < 4096; i += 256){ int2 v2 = L2c[i]; rc += (v2.x == 2*i) + (v2.y == 2*i + 1); }

    int v0 = pix, v1 = edges, v2 = runs, v3 = rc;
    for(int off = 32; off; off >>= 1){
        v0 += __shfl_down(v0, off, 64);
        v1 += __shfl_down(v1, off, 64);
        v2 += __shfl_down(v2, off, 64);
        v3 += __shfl_down(v3, off, 64);
    }
    __syncthreads();
    if(lane == 0){ red[wave*4] = v0; red[wave*4+1] = v1; red[wave*4+2] = v2; red[wave*4+3] = v3; }
    __syncthreads();
    if(tid == 0){
        int Pp = 0, E = 0, R = 0, RC = 0;
        for(int k2 = 0; k2 < 4; k2++){ Pp += red[k2*4]; E += red[k2*4+1]; R += red[k2*4+2]; RC += red[k2*4+3]; }
        const int B = RC - 8192 + R;                         // roots among real runs
        const float b0f = (float)B;
        const float b1f = b0f - ((float)Pp - (float)E);      // b1 = b0 - (pix - edges)
        const size_t o = (((size_t)ch * 100 + t) * 4 + r) * 2;
        betti[o] = b0f; betti[o + 1] = b1f;
    }
}

// One block per (region, code-column) row; accumulates into out[0]
// (zeroed by ccl block 0) with a device-scope float atomicAdd.
__global__ __launch_bounds__(128) void rows_kernel(const float* __restrict__ betti,
                                                   const float* __restrict__ gt,
                                                   float*       __restrict__ out){
    __shared__ float codes[100];
    __shared__ float birth[99], bs0[99], bs1[99], gs0[99], gs1[99];
    __shared__ float gsh[198];
    __shared__ float red[4];
    const int row = blockIdx.x;          // r*6 + j
    const int r = row / 6, j = row % 6;
    const int chmap[6] = {0, 0, 1, 1, 0, 0};   // inside, boundary, union(=inside)
    const int ch = chmap[j], comp = j & 1;
    const int tid = threadIdx.x;

    if(tid < 100) codes[tid] = betti[(((size_t)ch * 100 + tid) * 4 + r) * 2 + comp];
    const float* g = gt + (size_t)row * 99 * 2;
    for(int i = tid; i < 198; i += 128) gsh[i] = g[i];
    __syncthreads();

    float b = 0.f, d = 0.f;
    if(tid < 99){
        const float dv = codes[tid + 1] - codes[tid];
        const float thv = (float)tid / 99.0f;
        b = (dv > 0.f) ? thv : 0.f;
        d = (dv < 0.f) ? thv : 0.f;
        birth[tid] = b;
    }
    __syncthreads();

    if(tid < 99){
        // stable sort by birth == stable partition (positive births already ascending)
        int zb = 0, tz = 0;
        for(int k = 0; k < 99; k++){
            const int z = (birth[k] == 0.f) ? 1 : 0;
            tz += z;
            if(k < tid) zb += z;
        }
        const int pos = (b == 0.f) ? zb : (tz + tid - zb);
        bs0[pos] = b; bs1[pos] = d;

        const float gb = gsh[tid * 2];
        int rank = 0;
        for(int k = 0; k < 99; k++){
            const float o = gsh[k * 2];
            rank += (o < gb || (o == gb && k < tid)) ? 1 : 0;
        }
        gs0[rank] = gb; gs1[rank] = gsh[tid * 2 + 1];
    }
    __syncthreads();

    float mm = 0.f, u = 0.f;
    if(tid < 99){
        mm = fabsf(bs0[tid] - gs0[tid]) + fabsf(bs1[tid] - gs1[tid]);
        u = d - b;
    }
    for(int off = 32; off; off >>= 1){
        mm += __shfl_down(mm, off, 64);
        u  += __shfl_down(u,  off, 64);
    }
    if((tid & 63) == 0){ red[(tid >> 6)*2] = mm; red[(tid >> 6)*2 + 1] = u; }
    __syncthreads();
    if(tid == 0)
        atomicAdd(out, (red[0] + red[2]) / 2376.0f + (red[1] + red[3]) / 24.0f);
}

extern "C" void kernel_launch(void* const* d_in, const int* in_sizes, int n_in,
                              void* d_out, int out_size, void* d_ws, size_t ws_size,
                              hipStream_t stream){
    const float* prob = (const float*)d_in[0];   // [4,3,128,128] f32
    const int*   sel  = (const int*)d_in[1];     // [4]
    const float* gt   = (const float*)d_in[2];   // [4,6,99,2] f32
    float* betti = (float*)d_ws;                 // [2][100][4][2] = 1600 floats

    ccl_kernel <<<800, 256, 0, stream>>>(prob, sel, betti, (float*)d_out);
    rows_kernel<<<24, 128, 0, stream>>>(betti, gt, (float*)d_out);
}

// Round 6
// 103.430 us; speedup vs baseline: 1.7049x; 1.1581x over previous
//
#include <hip/hip_runtime.h>

typedef unsigned long long u64;

__device__ __forceinline__ int find_root(int* L, int a){
    int p = L[a];
    while(p != a){
        int gp = L[p];
        if(gp != p) L[a] = gp;   // path halving; benign race
        a = p; p = gp;
    }
    return a;
}

// Link-by-index (root hi -> lo): links strictly decrease => acyclic under
// concurrency. Every successful CAS merges exactly two distinct trees, so
// returning the success count lets b0 = total_runs - sum(successes).
__device__ __forceinline__ int unite(int* L, int a, int b){
    while(true){
        a = find_root(L, a);
        b = find_root(L, b);
        if(a == b) return 0;
        int hi = (a > b) ? a : b;
        int lo = (a > b) ? b : a;
        int old = atomicCAS(&L[hi], hi, lo);
        if(old == hi) return 1;
        a = old; b = lo;
    }
}

// One block per (ch, threshold, region). Rows as 2x u64 ballot-built bitmasks.
// pix/edges via popcounts. Union-find over RUNS with compact ids (prefix sum
// of per-word run counts). b0 = runs - merges: NO arena scan. 5 barriers.
__global__ __launch_bounds__(256) void ccl_kernel(const float* __restrict__ prob,
                                                  const int*   __restrict__ sel,
                                                  float*       __restrict__ betti,
                                                  float*       __restrict__ out){
    __shared__ u64 M[256];     // row masks: word w = (row<<1)|half
    __shared__ u64 S[256];     // run-start masks
    __shared__ int Pr[257];    // exclusive prefix of per-word run counts
    __shared__ int L[8192];    // union-find arena (32 KB), only [0,R) used
    __shared__ int red[12];
    const int tid = threadIdx.x, bid = blockIdx.x;
    if(bid == 0 && tid == 0) atomicExch(out, 0.0f);   // zero for rows' atomicAdd
    const int ch = bid / 400, t = (bid % 400) >> 2, r = bid & 3;
    const float th = (float)t / 99.0f;
    const float* img = prob + (size_t)(sel[r] * 3 + ch) * 16384;

    // build bitmasks: wave's ballot over 64 consecutive pixels = one u64 word
    const int lane = tid & 63, wave = tid >> 6;
    for(int c = 0; c < 64; c++){
        float v = img[c * 256 + wave * 64 + lane];
        u64 mm = __ballot(v > th);
        if(lane == 0) M[c * 4 + wave] = mm;
    }
    __syncthreads();                                       // B1: M complete

    // per-word masks & counts (thread <-> word)
    const int w = tid, row = w >> 1, half = w & 1;
    const u64 m = M[w];
    const u64 lcar = half ? (M[w - 1] >> 63) : 0ULL;
    const u64 s = m & ~((m << 1) | lcar);
    S[w] = s;
    int pix   = __popcll(m);
    int edges = __popcll(m & ((m << 1) | lcar));           // horizontal pairs
    const u64 va = (row > 0) ? M[w - 2] : 0ULL;
    edges += __popcll(m & va);                              // vertical pairs
    const int runs = __popcll(s);

    // exclusive prefix sum of runs over the 256 words -> compact run ids
    int incl = runs;
    for(int off = 1; off < 64; off <<= 1){
        int n = __shfl_up(incl, off, 64);
        if(lane >= off) incl += n;
    }
    if(lane == 63) red[wave] = incl;
    __syncthreads();                                       // B2: S + wave totals
    int woff = 0;
    for(int k = 0; k < wave; k++) woff += red[k];
    const int excl = woff + incl - runs;                   // == Pr[w]
    Pr[w] = excl;
    if(w == 255) Pr[256] = excl + runs;
    __syncthreads();                                       // B3: Pr complete
    const int R = Pr[256];

    {   // arena init: only the R live nodes (rounded up to int4)
        int4* L4 = (int4*)L;
        const int n4 = (R + 3) >> 2;
        for(int i = tid; i < n4; i += 256){ int b = i * 4; L4[i] = make_int4(b, b+1, b+2, b+3); }
    }
    __syncthreads();                                       // B4: arena ready

    // per-word divergent union loop over vertical contact-segment starts
    int merges = 0;
    if(row > 0){
        u64 c = m & va;
        if(c){
            const u64 ccar = half ? ((M[w - 1] & M[w - 3]) >> 63) : 0ULL;
            u64 cs = c & ~((c << 1) | ccar);
            if(cs){
                const u64 sa = S[w - 2];
                const int Pa = Pr[w - 2];
                do{
                    const int x = __ffsll(cs) - 1;
                    cs &= cs - 1;
                    const u64 lm = (2ULL << x) - 1;        // bits [0..x]
                    const int nb = excl + __popcll(s  & lm) - 1;
                    const int na = Pa   + __popcll(sa & lm) - 1;
                    merges += unite(L, na, nb);
                }while(cs);
            }
        }
    }
    // merges are per-thread registers: no barrier needed for the sum itself,
    // only before reusing red[] (B5 below).

    int v0 = pix, v1 = edges, v2 = merges;
    for(int off = 32; off; off >>= 1){
        v0 += __shfl_down(v0, off, 64);
        v1 += __shfl_down(v1, off, 64);
        v2 += __shfl_down(v2, off, 64);
    }
    __syncthreads();                                       // B5: red[] reusable
    if(lane == 0){ red[wave*3] = v0; red[wave*3+1] = v1; red[wave*3+2] = v2; }
    __syncthreads();
    if(tid == 0){
        int P = 0, E = 0, MG = 0;
        for(int k = 0; k < 4; k++){ P += red[k*3]; E += red[k*3+1]; MG += red[k*3+2]; }
        const float b0f = (float)(R - MG);                 // components = nodes - links
        const float b1f = b0f - ((float)P - (float)E);     // b1 = b0 - (pix - edges)
        const size_t o = (((size_t)ch * 100 + t) * 4 + r) * 2;
        betti[o] = b0f; betti[o + 1] = b1f;
    }
}

// One block per (region, code-column) row; accumulates into out[0]
// (zeroed by ccl block 0) with a device-scope float atomicAdd.
__global__ __launch_bounds__(128) void rows_kernel(const float* __restrict__ betti,
                                                   const float* __restrict__ gt,
                                                   float*       __restrict__ out){
    __shared__ float codes[100];
    __shared__ float birth[99], bs0[99], bs1[99], gs0[99], gs1[99];
    __shared__ float gsh[198];
    __shared__ float red[4];
    const int row = blockIdx.x;          // r*6 + j
    const int r = row / 6, j = row % 6;
    const int chmap[6] = {0, 0, 1, 1, 0, 0};   // inside, boundary, union(=inside)
    const int ch = chmap[j], comp = j & 1;
    const int tid = threadIdx.x;

    if(tid < 100) codes[tid] = betti[(((size_t)ch * 100 + tid) * 4 + r) * 2 + comp];
    const float* g = gt + (size_t)row * 99 * 2;
    for(int i = tid; i < 198; i += 128) gsh[i] = g[i];
    __syncthreads();

    float b = 0.f, d = 0.f;
    if(tid < 99){
        const float dv = codes[tid + 1] - codes[tid];
        const float thv = (float)tid / 99.0f;
        b = (dv > 0.f) ? thv : 0.f;
        d = (dv < 0.f) ? thv : 0.f;
        birth[tid] = b;
    }
    __syncthreads();

    if(tid < 99){
        // stable sort by birth == stable partition (positive births already ascending)
        int zb = 0, tz = 0;
        for(int k = 0; k < 99; k++){
            const int z = (birth[k] == 0.f) ? 1 : 0;
            tz += z;
            if(k < tid) zb += z;
        }
        const int pos = (b == 0.f) ? zb : (tz + tid - zb);
        bs0[pos] = b; bs1[pos] = d;

        const float gb = gsh[tid * 2];
        int rank = 0;
        for(int k = 0; k < 99; k++){
            const float o = gsh[k * 2];
            rank += (o < gb || (o == gb && k < tid)) ? 1 : 0;
        }
        gs0[rank] = gb; gs1[rank] = gsh[tid * 2 + 1];
    }
    __syncthreads();

    float mm = 0.f, u = 0.f;
    if(tid < 99){
        mm = fabsf(bs0[tid] - gs0[tid]) + fabsf(bs1[tid] - gs1[tid]);
        u = d - b;
    }
    for(int off = 32; off; off >>= 1){
        mm += __shfl_down(mm, off, 64);
        u  += __shfl_down(u,  off, 64);
    }
    if((tid & 63) == 0){ red[(tid >> 6)*2] = mm; red[(tid >> 6)*2 + 1] = u; }
    __syncthreads();
    if(tid == 0)
        atomicAdd(out, (red[0] + red[2]) / 2376.0f + (red[1] + red[3]) / 24.0f);
}

extern "C" void kernel_launch(void* const* d_in, const int* in_sizes, int n_in,
                              void* d_out, int out_size, void* d_ws, size_t ws_size,
                              hipStream_t stream){
    const float* prob = (const float*)d_in[0];   // [4,3,128,128] f32
    const int*   sel  = (const int*)d_in[1];     // [4]
    const float* gt   = (const float*)d_in[2];   // [4,6,99,2] f32
    float* betti = (float*)d_ws;                 // [2][100][4][2] = 1600 floats

    ccl_kernel <<<800, 256, 0, stream>>>(prob, sel, betti, (float*)d_out);
    rows_kernel<<<24, 128, 0, stream>>>(betti, gt, (float*)d_out);
}